// Round 16
// baseline (151.941 us; speedup 1.0000x reference)
//
#include <hip/hip_runtime.h>
#include <hip/hip_bf16.h>
#include <stdint.h>

#define CH   384
#define HID  512
#define NHD  8
#define MTOT 32768   // B*H*W tokens

typedef __attribute__((ext_vector_type(8))) short bf16x8;
typedef __attribute__((ext_vector_type(4))) float f32x4;
typedef unsigned short u16;

__device__ __forceinline__ float bf2f(u16 v){ return __uint_as_float(((unsigned)v)<<16); }
__device__ __forceinline__ u16 f2bf(float f){
  unsigned u = __float_as_uint(f);
  return (u16)((u + 0x7fffu + ((u>>16)&1u)) >> 16);
}
__device__ __forceinline__ float fast_tanh(float s){
  float e = __expf(2.f*s);
  return 1.f - 2.f*__builtin_amdgcn_rcpf(e + 1.f);
}
__device__ __forceinline__ void gload_lds16(const void* g, void* l){
  __builtin_amdgcn_global_load_lds((const __attribute__((address_space(1))) void*)g,
                                   (__attribute__((address_space(3))) void*)l, 16, 0, 0);
}

// ---------------- fused fp32 -> bf16 convert (x, W1, W2 in one launch) ----------------
#define CVT_N1 (MTOT*CH/4)        // 3145728 float4s
#define CVT_N2 (3*HID*CH/4)       // 147456
#define CVT_N3 (CH*HID/4)         // 49152
__global__ void k_cvt3(const float* __restrict__ x,  u16* __restrict__ xo,
                       const float* __restrict__ w1, u16* __restrict__ w1o,
                       const float* __restrict__ w2, u16* __restrict__ w2o){
  const int total = CVT_N1 + CVT_N2 + CVT_N3;
  int i = blockIdx.x*blockDim.x + threadIdx.x;
  int stride = gridDim.x*blockDim.x;
  for (; i < total; i += stride){
    const float4* src; ushort4* dst; int k;
    if (i < CVT_N1){ src = (const float4*)x;  dst = (ushort4*)xo;  k = i; }
    else if (i < CVT_N1 + CVT_N2){ src = (const float4*)w1; dst = (ushort4*)w1o; k = i - CVT_N1; }
    else { src = (const float4*)w2; dst = (ushort4*)w2o; k = i - CVT_N1 - CVT_N2; }
    float4 v = src[k];
    ushort4 o; o.x=f2bf(v.x); o.y=f2bf(v.y); o.z=f2bf(v.z); o.w=f2bf(v.w);
    dst[k] = o;
  }
}

// ---------------- GEMM1 v10: v8 (proven 63.5us) + aw repack add-on ----------------
// Repack: block bid also converts aw tile bid (64x96 fp32) to bf16 fragment-packed
// [tile][ks][mi][lane][8] with wts folded into ks=2, using gemm1's idle HBM/VMEM.
__global__ __launch_bounds__(256)
void k_gemm1(const u16* __restrict__ xb, const u16* __restrict__ w1b,
             const float* __restrict__ b1,
             u16* __restrict__ xh, u16* __restrict__ yb,
             const float* __restrict__ awf, const float* __restrict__ wts,
             u16* __restrict__ awb)
{
  __shared__ short lds[14336];  // A [0,8192)  B [8192,14336)  (28KB)
  const int tid = threadIdx.x;
  const int w = tid >> 6, lw = tid & 63;
  const int bid = blockIdx.x;
  const int xcd = bid & 7, ii = bid >> 3;
  const int m0 = (xcd*32 + (ii >> 4)) * 128;
  const int h0 = (ii & 15) * 32;
  const int lc = lw & 15, lk = lw >> 4;

  f32x4 acc[2][6] = {};   // [mi][seg*2+f]

  const int sl = (lw & 7) ^ (lw >> 3);
  const int rsub = lw >> 3;
  const u16* gsrc[7]; int ldst[7];
  #pragma unroll
  for (int i = 0; i < 7; ++i){
    int c = w*7 + i;
    if (c < 16){
      int r = c*8 + rsub;
      gsrc[i] = xb + (size_t)(m0 + r)*CH + sl*8;
      ldst[i] = c*512;
    } else {
      int rb = (c-16)*8 + rsub;                 // 0..95
      int grow = (rb >> 5)*HID + h0 + (rb & 31);
      gsrc[i] = w1b + (size_t)grow*CH + sl*8;
      ldst[i] = 8192 + (c-16)*512;
    }
  }

  #pragma unroll 1
  for (int kt = 0; kt < 6; ++kt){
    #pragma unroll
    for (int i = 0; i < 7; ++i)
      gload_lds16(gsrc[i] + kt*64, &lds[ldst[i]]);
    __syncthreads();
    #pragma unroll
    for (int ks = 0; ks < 2; ++ks){
      const int s = (ks*4 + lk) ^ (lc & 7);
      bf16x8 af[2], bfr[6];
      #pragma unroll
      for (int mi = 0; mi < 2; ++mi){
        int row = w*32 + mi*16 + lc;
        af[mi] = *(const bf16x8*)&lds[row*64 + s*8];
      }
      #pragma unroll
      for (int nj = 0; nj < 6; ++nj){
        int row = nj*16 + lc;
        bfr[nj] = *(const bf16x8*)&lds[8192 + row*64 + s*8];
      }
      #pragma unroll
      for (int mi = 0; mi < 2; ++mi)
        #pragma unroll
        for (int nj = 0; nj < 6; ++nj)
          acc[mi][nj] = __builtin_amdgcn_mfma_f32_16x16x32_bf16(af[mi], bfr[nj], acc[mi][nj], 0,0,0);
    }
    __syncthreads();
  }

  // ---- aw repack add-on (independent of GEMM state; loads overlap epilogue) ----
  if (awb){
    const int tile = bid;
    const float* awt = awf + (size_t)tile*6144;
    u16* awo = awb + (size_t)tile*6144;
    #pragma unroll
    for (int rep = 0; rep < 3; ++rep){
      int c = tid + rep*256;           // chunk id; ks == rep
      int mi = (c >> 6) & 3;
      int lane = c & 63;
      const float* p = awt + (mi*16 + (lane&15))*96 + rep*32 + (lane>>4)*8;
      float4 f0 = *(const float4*)p, f1 = *(const float4*)(p+4);
      float t[8] = {f0.x,f0.y,f0.z,f0.w,f1.x,f1.y,f1.z,f1.w};
      if (rep == 2){
        const float* wp = wts + (size_t)(tile & 511)*32 + (lane>>4)*8;
        float4 a = *(const float4*)wp, cc = *(const float4*)(wp+4);
        float wv8[8] = {a.x,a.y,a.z,a.w,cc.x,cc.y,cc.z,cc.w};
        #pragma unroll
        for (int j = 0; j < 8; ++j) t[j] *= wv8[j];
      }
      bf16x8 o;
      #pragma unroll
      for (int j = 0; j < 8; ++j) o[j] = (short)f2bf(t[j]);
      *(bf16x8*)&awo[c*8] = o;
    }
  }

  // ---- epilogue: bias + x*tanh(s), coalesced store via per-wave LDS transpose ----
  {
    short* epx = &lds[w*2560];          // 32 rows x 40-short pitch
    short* epy = &lds[w*2560 + 1280];
    float bs[2], bx[2], by[2];
    #pragma unroll
    for (int f = 0; f < 2; ++f){
      int col = h0 + f*16 + lc;
      bs[f] = b1[col]; bx[f] = b1[512 + col]; by[f] = b1[1024 + col];
    }
    #pragma unroll
    for (int mi = 0; mi < 2; ++mi)
      #pragma unroll
      for (int f = 0; f < 2; ++f)
        #pragma unroll
        for (int j = 0; j < 4; ++j){
          float sv = acc[mi][0+f][j] + bs[f];
          float xv = (acc[mi][2+f][j] + bx[f]) * fast_tanh(sv);
          float yv = acc[mi][4+f][j] + by[f];
          int row = mi*16 + lk*4 + j;
          epx[row*40 + f*16 + lc] = (short)f2bf(xv);
          epy[row*40 + f*16 + lc] = (short)f2bf(yv);
        }
    __syncthreads();
    const int row = lw >> 1, half = lw & 1;
    const size_t gbase = (size_t)(m0 + w*32 + row)*HID + h0 + half*16;
    #pragma unroll
    for (int q = 0; q < 2; ++q){
      bf16x8 v = *(const bf16x8*)&epx[row*40 + half*16 + q*8];
      *(bf16x8*)&xh[gbase + q*8] = v;
    }
    #pragma unroll
    for (int q = 0; q < 2; ++q){
      bf16x8 v = *(const bf16x8*)&epy[row*40 + half*16 + q*8];
      *(bf16x8*)&yb[gbase + q*8] = v;
    }
  }
}

// ---------------- Attention v7: packed-aw path (aw pre-converted/folded by gemm1) ----------------
__global__ __launch_bounds__(64, 3)
void k_attn_pk(const u16* __restrict__ awb, const int* __restrict__ idxs,
               const u16* __restrict__ xh, const u16* __restrict__ yb,
               u16* __restrict__ zb)
{
  __shared__ short lKv[64*96];   // kv^T swizzled; reused as y[q][d] pitch-72 post-MFMA
  const int tid = threadIdx.x;   // one wave
  const int bid = blockIdx.x;    // ((h*8+b)*64+n)
  const int h = bid >> 9;
  const int b = (bid >> 6) & 7;
  const int n = bid & 63;
  const int bh = n >> 3, bw = n & 7;

  // ---- stage kv^T: 48 token-pairs x 8 dim-groups, pure bf16 copy ----
  {
    const int dg = tid & 7;
    const int pr = tid >> 3;
    #pragma unroll
    for (int it = 0; it < 6; ++it){
      int pair = it*8 + pr;
      int t0 = pair*2;
      size_t r0, r1;
      if (t0 < 64){
        int pix = (bh*8 + (t0>>3))*64 + bw*8 + (t0&7);
        r0 = (size_t)b*4096 + pix;
        r1 = r0 + 1;
      } else {
        int e = (b*64+n)*32 + (t0-64);
        r0 = (size_t)b*4096 + idxs[e];
        r1 = (size_t)b*4096 + idxs[e+1];
      }
      bf16x8 v0 = *(const bf16x8*)&xh[r0*HID + h*64 + dg*8];
      bf16x8 v1 = *(const bf16x8*)&xh[r1*HID + h*64 + dg*8];
      #pragma unroll
      for (int j = 0; j < 8; ++j){
        int d = dg*8 + j;
        int elem = (d*96 + t0) ^ (dg<<3);
        unsigned pk = (unsigned)(u16)v0[j] | ((unsigned)(u16)v1[j] << 16);
        *(unsigned*)&lKv[elem] = pk;
      }
    }
  }
  __syncthreads();

  // ---- A-fragments: 12 coalesced 16B loads from packed aw ----
  bf16x8 af[3][4];
  {
    const u16* awp = awb + (size_t)bid*6144 + tid*8;
    #pragma unroll
    for (int ks = 0; ks < 3; ++ks)
      #pragma unroll
      for (int mi = 0; mi < 4; ++mi)
        af[ks][mi] = *(const bf16x8*)&awp[(ks*256 + mi*64)*8];
  }

  // ---- y-row prefetch (lane q owns row q): 8x16B, latency hides under MFMA ----
  bf16x8 yv[8];
  {
    int pix = (bh*8 + (tid>>3))*64 + bw*8 + (tid&7);
    const u16* yrow = yb + ((size_t)b*4096 + pix)*HID + h*64;
    #pragma unroll
    for (int c = 0; c < 8; ++c)
      yv[c] = *(const bf16x8*)&yrow[c*8];
  }

  // ---- MFMA: 64x96 @ 96x64 ----
  f32x4 acc[4][4] = {};
  const int lc = tid & 15, lk = tid >> 4;
  #pragma unroll
  for (int ks = 0; ks < 3; ++ks){
    bf16x8 bv[4];
    #pragma unroll
    for (int nj = 0; nj < 4; ++nj){
      int d = nj*16 + lc;
      int idx = (d*96 + ks*32 + lk*8) ^ ((d>>3)<<3);
      bv[nj] = *(const bf16x8*)&lKv[idx];
    }
    #pragma unroll
    for (int mi = 0; mi < 4; ++mi)
      #pragma unroll
      for (int nj = 0; nj < 4; ++nj)
        acc[mi][nj] = __builtin_amdgcn_mfma_f32_16x16x32_bf16(af[ks][mi], bv[nj], acc[mi][nj], 0,0,0);
  }

  // ---- y transpose through LDS (kv region dead): yl[q][d], pitch 72 shorts ----
  {
    const int q = tid;
    #pragma unroll
    for (int c = 0; c < 8; ++c)
      *(bf16x8*)&lKv[q*72 + c*8] = yv[c];
  }

  // ---- epilogue: z = out * y, v2 store pattern, y from LDS ----
  #pragma unroll
  for (int mi = 0; mi < 4; ++mi){
    #pragma unroll
    for (int nj = 0; nj < 4; ++nj){
      int d = nj*16 + lc;
      size_t gcol = (size_t)h*64 + d;
      #pragma unroll
      for (int j = 0; j < 4; ++j){
        int q = mi*16 + lk*4 + j;
        int pix = (bh*8 + (q>>3))*64 + bw*8 + (q&7);
        size_t r = (size_t)b*4096 + pix;
        float yvf = bf2f((u16)lKv[q*72 + d]);
        zb[r*HID + gcol] = f2bf(acc[mi][nj][j] * yvf);
      }
    }
  }
}

// ---------------- Attention fallback (round-15 v6, proven) ----------------
__global__ __launch_bounds__(64, 3)
void k_attn(const float* __restrict__ aw, const float* __restrict__ wts,
            const int* __restrict__ idxs,
            const u16* __restrict__ xh, const u16* __restrict__ yb,
            u16* __restrict__ zb)
{
  __shared__ short lKv[64*96];
  const int tid = threadIdx.x;
  const int bid = blockIdx.x;
  const int h = bid >> 9;
  const int b = (bid >> 6) & 7;
  const int n = bid & 63;
  const int bh = n >> 3, bw = n & 7;

  {
    const int dg = tid & 7;
    const int pr = tid >> 3;
    #pragma unroll
    for (int it = 0; it < 6; ++it){
      int pair = it*8 + pr;
      int t0 = pair*2;
      size_t r0, r1;
      if (t0 < 64){
        int pix = (bh*8 + (t0>>3))*64 + bw*8 + (t0&7);
        r0 = (size_t)b*4096 + pix;
        r1 = r0 + 1;
      } else {
        int e = (b*64+n)*32 + (t0-64);
        r0 = (size_t)b*4096 + idxs[e];
        r1 = (size_t)b*4096 + idxs[e+1];
      }
      bf16x8 v0 = *(const bf16x8*)&xh[r0*HID + h*64 + dg*8];
      bf16x8 v1 = *(const bf16x8*)&xh[r1*HID + h*64 + dg*8];
      #pragma unroll
      for (int j = 0; j < 8; ++j){
        int d = dg*8 + j;
        int elem = (d*96 + t0) ^ (dg<<3);
        unsigned pk = (unsigned)(u16)v0[j] | ((unsigned)(u16)v1[j] << 16);
        *(unsigned*)&lKv[elem] = pk;
      }
    }
  }
  __syncthreads();

  float wv[8];
  {
    const float* wp = wts + (size_t)(b*64+n)*32 + (tid>>4)*8;
    float4 a = *(const float4*)wp, c = *(const float4*)(wp+4);
    wv[0]=a.x; wv[1]=a.y; wv[2]=a.z; wv[3]=a.w;
    wv[4]=c.x; wv[5]=c.y; wv[6]=c.z; wv[7]=c.w;
  }
  const float* awp = aw + (size_t)bid * (64*96);
  bf16x8 af[3][4];
  #pragma unroll
  for (int ks = 0; ks < 3; ++ks){
    #pragma unroll
    for (int mi = 0; mi < 4; ++mi){
      const float* p = awp + (size_t)(mi*16 + (tid&15))*96 + ks*32 + (tid>>4)*8;
      float4 f0 = *(const float4*)p;
      float4 f1 = *(const float4*)(p+4);
      float t[8] = {f0.x,f0.y,f0.z,f0.w,f1.x,f1.y,f1.z,f1.w};
      #pragma unroll
      for (int j = 0; j < 8; ++j){
        float v = (ks == 2) ? t[j]*wv[j] : t[j];
        af[ks][mi][j] = (short)f2bf(v);
      }
    }
  }

  bf16x8 yv[8];
  {
    int pix = (bh*8 + (tid>>3))*64 + bw*8 + (tid&7);
    const u16* yrow = yb + ((size_t)b*4096 + pix)*HID + h*64;
    #pragma unroll
    for (int c = 0; c < 8; ++c)
      yv[c] = *(const bf16x8*)&yrow[c*8];
  }

  f32x4 acc[4][4] = {};
  const int lc = tid & 15, lk = tid >> 4;
  #pragma unroll
  for (int ks = 0; ks < 3; ++ks){
    bf16x8 bv[4];
    #pragma unroll
    for (int nj = 0; nj < 4; ++nj){
      int d = nj*16 + lc;
      int idx = (d*96 + ks*32 + lk*8) ^ ((d>>3)<<3);
      bv[nj] = *(const bf16x8*)&lKv[idx];
    }
    #pragma unroll
    for (int mi = 0; mi < 4; ++mi)
      #pragma unroll
      for (int nj = 0; nj < 4; ++nj)
        acc[mi][nj] = __builtin_amdgcn_mfma_f32_16x16x32_bf16(af[ks][mi], bv[nj], acc[mi][nj], 0,0,0);
  }

  {
    const int q = tid;
    #pragma unroll
    for (int c = 0; c < 8; ++c)
      *(bf16x8*)&lKv[q*72 + c*8] = yv[c];
  }

  #pragma unroll
  for (int mi = 0; mi < 4; ++mi){
    #pragma unroll
    for (int nj = 0; nj < 4; ++nj){
      int d = nj*16 + lc;
      size_t gcol = (size_t)h*64 + d;
      #pragma unroll
      for (int j = 0; j < 4; ++j){
        int q = mi*16 + lk*4 + j;
        int pix = (bh*8 + (q>>3))*64 + bw*8 + (q&7);
        size_t r = (size_t)b*4096 + pix;
        float yvf = bf2f((u16)lKv[q*72 + d]);
        zb[r*HID + gcol] = f2bf(acc[mi][nj][j] * yvf);
      }
    }
  }
}

// ---------------- GEMM2 v6: BK=32 dbuf, counted vmcnt (unchanged, passing) ----------------
__global__ __launch_bounds__(256)
void k_gemm2(const u16* __restrict__ zb, const u16* __restrict__ w2b,
             const float* __restrict__ b2, float* __restrict__ out)
{
  __shared__ short lds[16384];  // 32KB: buf stride 8192 shorts (A 4096 + B 4096)
  const int tid = threadIdx.x;
  const int w = tid>>6, lw = tid&63;
  const int wm = w>>1, wn = w&1;
  const int bid = blockIdx.x;
  const int xcd = bid & 7, ii = bid >> 3;
  const int m0 = (xcd*32 + ii/3) * 128;
  const int n0 = (ii%3) * 128;
  const int lc = lw & 15, lk = lw >> 4;

  f32x4 acc[4][4] = {};

  const int sl_g = (lw & 3) ^ ((lw >> 3) & 3);
  const int rsub = lw >> 2;
  const u16* gsrc[4]; int ldst[4];
  #pragma unroll
  for (int i = 0; i < 4; ++i){
    int c = w*4 + i;
    if (c < 8){
      int r = c*16 + rsub;
      gsrc[i] = zb + (size_t)(m0+r)*HID + sl_g*8;
      ldst[i] = c*512;
    } else {
      int cb = c - 8;
      int r = cb*16 + rsub;
      gsrc[i] = w2b + (size_t)(n0+r)*HID + sl_g*8;
      ldst[i] = 4096 + cb*512;
    }
  }
  auto STAGE = [&](int buf, int kt){
    #pragma unroll
    for (int i = 0; i < 4; ++i)
      gload_lds16(gsrc[i] + kt*32, &lds[ldst[i] + buf*8192]);
  };
  const int skey = (lc >> 1) & 3;
  auto COMPUTE = [&](int buf){
    const short* pa = lds + buf*8192;
    const short* pb = lds + buf*8192 + 4096;
    bf16x8 af[4], bb[4];
    #pragma unroll
    for (int mi=0; mi<4; ++mi){
      int row = wm*64 + mi*16 + lc;
      af[mi] = *(const bf16x8*)&pa[row*32 + (lk ^ skey)*8];
    }
    #pragma unroll
    for (int nj=0; nj<4; ++nj){
      int row = wn*64 + nj*16 + lc;
      bb[nj] = *(const bf16x8*)&pb[row*32 + (lk ^ skey)*8];
    }
    #pragma unroll
    for (int mi=0; mi<4; ++mi)
      #pragma unroll
      for (int nj=0; nj<4; ++nj)
        acc[mi][nj] = __builtin_amdgcn_mfma_f32_16x16x32_bf16(af[mi], bb[nj], acc[mi][nj], 0,0,0);
  };

  STAGE(0, 0);
  #pragma unroll 1
  for (int kt = 0; kt < 16; ++kt){
    if (kt < 15){
      STAGE((kt+1)&1, kt+1);
      asm volatile("s_waitcnt vmcnt(4)" ::: "memory");
    } else {
      asm volatile("s_waitcnt vmcnt(0)" ::: "memory");
    }
    __builtin_amdgcn_sched_barrier(0);
    __builtin_amdgcn_s_barrier();
    COMPUTE(kt&1);
    __builtin_amdgcn_sched_barrier(0);
    __builtin_amdgcn_s_barrier();
  }

  const int lr4 = lk*4;
  #pragma unroll
  for (int nj=0; nj<4; ++nj){
    int col = n0 + wn*64 + nj*16 + lc;
    float bias = b2[col];
    #pragma unroll
    for (int mi=0; mi<4; ++mi){
      #pragma unroll
      for (int j=0; j<4; ++j){
        int row = m0 + wm*64 + mi*16 + lr4 + j;
        out[(size_t)row*CH + col] = acc[mi][nj][j] + bias;
      }
    }
  }
}

extern "C" void kernel_launch(void* const* d_in, const int* in_sizes, int n_in,
                              void* d_out, int out_size, void* d_ws, size_t ws_size,
                              hipStream_t stream) {
  const float* x   = (const float*)d_in[0];
  const float* aw  = (const float*)d_in[1];
  const float* wts = (const float*)d_in[2];
  const float* w1  = (const float*)d_in[3];
  const float* b1  = (const float*)d_in[4];
  const float* w2  = (const float*)d_in[5];
  const float* b2  = (const float*)d_in[6];
  const int*   idx = (const int*)d_in[7];
  float* out = (float*)d_out;

  char* ws = (char*)d_ws;
  u16* x_bf  = (u16*)(ws);                              // 25165824
  u16* w1_bf = (u16*)(ws + 25165824);                   // 1179648
  u16* w2_bf = (u16*)(ws + 26345472);                   // 393216
  u16* xh_bf = (u16*)(ws + 26738688);                   // 33554432
  u16* y_bf  = (u16*)(ws + 60293120);                   // 33554432
  u16* z_bf  = (u16*)(ws + 93847552);                   // 33554432
  const size_t need = 127401984ull + 50331648ull;       // + aw_bf (50.33 MB)
  u16* aw_bf = (ws_size >= need) ? (u16*)(ws + 127401984) : (u16*)nullptr;

  k_cvt3<<<2048, 256, 0, stream>>>(x, x_bf, w1, w1_bf, w2, w2_bf);

  k_gemm1<<<4096, 256, 0, stream>>>(x_bf, w1_bf, b1, xh_bf, y_bf, aw, wts, aw_bf);
  if (aw_bf)
    k_attn_pk<<<NHD*8*64, 64, 0, stream>>>(aw_bf, idx, xh_bf, y_bf, z_bf);
  else
    k_attn<<<NHD*8*64, 64, 0, stream>>>(aw, wts, idx, xh_bf, y_bf, z_bf);
  k_gemm2<<<768, 256, 0, stream>>>(z_bf, w2_bf, b2, out);
}

// Round 17
// 141.011 us; speedup vs baseline: 1.0775x; 1.0775x over previous
//
#include <hip/hip_runtime.h>
#include <hip/hip_bf16.h>
#include <stdint.h>

#define CH   384
#define HID  512
#define NHD  8
#define MTOT 32768   // B*H*W tokens

typedef __attribute__((ext_vector_type(8))) short bf16x8;
typedef __attribute__((ext_vector_type(4))) float f32x4;
typedef unsigned short u16;

__device__ __forceinline__ float bf2f(u16 v){ return __uint_as_float(((unsigned)v)<<16); }
__device__ __forceinline__ u16 f2bf(float f){
  unsigned u = __float_as_uint(f);
  return (u16)((u + 0x7fffu + ((u>>16)&1u)) >> 16);
}
__device__ __forceinline__ float fast_tanh(float s){
  float e = __expf(2.f*s);
  return 1.f - 2.f*__builtin_amdgcn_rcpf(e + 1.f);
}
__device__ __forceinline__ void gload_lds16(const void* g, void* l){
  __builtin_amdgcn_global_load_lds((const __attribute__((address_space(1))) void*)g,
                                   (__attribute__((address_space(3))) void*)l, 16, 0, 0);
}

// ---------------- fused fp32 -> bf16 convert (x, W1, W2 in one launch) ----------------
#define CVT_N1 (MTOT*CH/4)        // 3145728 float4s
#define CVT_N2 (3*HID*CH/4)       // 147456
#define CVT_N3 (CH*HID/4)         // 49152
__global__ void k_cvt3(const float* __restrict__ x,  u16* __restrict__ xo,
                       const float* __restrict__ w1, u16* __restrict__ w1o,
                       const float* __restrict__ w2, u16* __restrict__ w2o){
  const int total = CVT_N1 + CVT_N2 + CVT_N3;
  int i = blockIdx.x*blockDim.x + threadIdx.x;
  int stride = gridDim.x*blockDim.x;
  for (; i < total; i += stride){
    const float4* src; ushort4* dst; int k;
    if (i < CVT_N1){ src = (const float4*)x;  dst = (ushort4*)xo;  k = i; }
    else if (i < CVT_N1 + CVT_N2){ src = (const float4*)w1; dst = (ushort4*)w1o; k = i - CVT_N1; }
    else { src = (const float4*)w2; dst = (ushort4*)w2o; k = i - CVT_N1 - CVT_N2; }
    float4 v = src[k];
    ushort4 o; o.x=f2bf(v.x); o.y=f2bf(v.y); o.z=f2bf(v.z); o.w=f2bf(v.w);
    dst[k] = o;
  }
}

// ---------------- GEMM1 v8 (reverted, proven 63.5us): BM=128, BH=32, BK=64 ----------------
__global__ __launch_bounds__(256)
void k_gemm1(const u16* __restrict__ xb, const u16* __restrict__ w1b,
             const float* __restrict__ b1,
             u16* __restrict__ xh, u16* __restrict__ yb)
{
  __shared__ short lds[14336];  // A [0,8192)  B [8192,14336)  (28KB)
  const int tid = threadIdx.x;
  const int w = tid >> 6, lw = tid & 63;
  const int bid = blockIdx.x;
  const int xcd = bid & 7, ii = bid >> 3;
  const int m0 = (xcd*32 + (ii >> 4)) * 128;
  const int h0 = (ii & 15) * 32;
  const int lc = lw & 15, lk = lw >> 4;

  f32x4 acc[2][6] = {};   // [mi][seg*2+f]

  const int sl = (lw & 7) ^ (lw >> 3);
  const int rsub = lw >> 3;
  const u16* gsrc[7]; int ldst[7];
  #pragma unroll
  for (int i = 0; i < 7; ++i){
    int c = w*7 + i;
    if (c < 16){
      int r = c*8 + rsub;
      gsrc[i] = xb + (size_t)(m0 + r)*CH + sl*8;
      ldst[i] = c*512;
    } else {
      int rb = (c-16)*8 + rsub;                 // 0..95
      int grow = (rb >> 5)*HID + h0 + (rb & 31);
      gsrc[i] = w1b + (size_t)grow*CH + sl*8;
      ldst[i] = 8192 + (c-16)*512;
    }
  }

  #pragma unroll 1
  for (int kt = 0; kt < 6; ++kt){
    #pragma unroll
    for (int i = 0; i < 7; ++i)
      gload_lds16(gsrc[i] + kt*64, &lds[ldst[i]]);
    __syncthreads();
    #pragma unroll
    for (int ks = 0; ks < 2; ++ks){
      const int s = (ks*4 + lk) ^ (lc & 7);
      bf16x8 af[2], bfr[6];
      #pragma unroll
      for (int mi = 0; mi < 2; ++mi){
        int row = w*32 + mi*16 + lc;
        af[mi] = *(const bf16x8*)&lds[row*64 + s*8];
      }
      #pragma unroll
      for (int nj = 0; nj < 6; ++nj){
        int row = nj*16 + lc;
        bfr[nj] = *(const bf16x8*)&lds[8192 + row*64 + s*8];
      }
      #pragma unroll
      for (int mi = 0; mi < 2; ++mi)
        #pragma unroll
        for (int nj = 0; nj < 6; ++nj)
          acc[mi][nj] = __builtin_amdgcn_mfma_f32_16x16x32_bf16(af[mi], bfr[nj], acc[mi][nj], 0,0,0);
    }
    __syncthreads();
  }

  {
    short* epx = &lds[w*2560];          // 32 rows x 40-short pitch
    short* epy = &lds[w*2560 + 1280];
    float bs[2], bx[2], by[2];
    #pragma unroll
    for (int f = 0; f < 2; ++f){
      int col = h0 + f*16 + lc;
      bs[f] = b1[col]; bx[f] = b1[512 + col]; by[f] = b1[1024 + col];
    }
    #pragma unroll
    for (int mi = 0; mi < 2; ++mi)
      #pragma unroll
      for (int f = 0; f < 2; ++f)
        #pragma unroll
        for (int j = 0; j < 4; ++j){
          float sv = acc[mi][0+f][j] + bs[f];
          float xv = (acc[mi][2+f][j] + bx[f]) * fast_tanh(sv);
          float yv = acc[mi][4+f][j] + by[f];
          int row = mi*16 + lk*4 + j;
          epx[row*40 + f*16 + lc] = (short)f2bf(xv);
          epy[row*40 + f*16 + lc] = (short)f2bf(yv);
        }
    __syncthreads();
    const int row = lw >> 1, half = lw & 1;
    const size_t gbase = (size_t)(m0 + w*32 + row)*HID + h0 + half*16;
    #pragma unroll
    for (int q = 0; q < 2; ++q){
      bf16x8 v = *(const bf16x8*)&epx[row*40 + half*16 + q*8];
      *(bf16x8*)&xh[gbase + q*8] = v;
    }
    #pragma unroll
    for (int q = 0; q < 2; ++q){
      bf16x8 v = *(const bf16x8*)&epy[row*40 + half*16 + q*8];
      *(bf16x8*)&yb[gbase + q*8] = v;
    }
  }
}

// ---------------- Attention v9: aw tile staged via global_load_lds (24KB in flight) ----------------
// aw tile (64x96 fp32, contiguous 24KB) staged with source-swizzled gload_lds16
// (slice ^= row&7 within 8-slice groups; slices/row=24). Fragments read from LDS
// conflict-free, wts folded at read. kv gather + y prefetch overlap the staging.
__global__ __launch_bounds__(64, 3)
void k_attn(const float* __restrict__ aw, const float* __restrict__ wts,
            const int* __restrict__ idxs,
            const u16* __restrict__ xh, const u16* __restrict__ yb,
            u16* __restrict__ zb)
{
  __shared__ short ldsb[6144 + 12288];   // kv bf16 [0,6144); aw fp32 at short-ofs 6144 (24KB)
  short* lKv = ldsb;
  float* lAw = (float*)&ldsb[6144];
  const int tid = threadIdx.x;   // one wave
  const int bid = blockIdx.x;    // ((h*8+b)*64+n)
  const int h = bid >> 9;
  const int b = (bid >> 6) & 7;
  const int n = bid & 63;
  const int bh = n >> 3, bw = n & 7;

  // ---- 1. aw staging: 24 x gload_lds16, pre-swizzled source, linear LDS ----
  {
    const float* awt = aw + (size_t)bid * 6144;
    #pragma unroll
    for (int i = 0; i < 24; ++i){
      int s = i*64 + tid;                 // dest 16B-slice index (0..1535)
      int row = s / 24;                   // u24 magic div
      int sir = s - row*24;               // slice-in-row 0..23
      int src = row*24 + (sir ^ (row & 7));
      gload_lds16(awt + src*4, (char*)lAw + (size_t)i*1024);
    }
  }

  // ---- 2. kv gather -> kvT LDS (overlaps aw staging in flight) ----
  {
    const int dg = tid & 7;
    const int pr = tid >> 3;
    #pragma unroll
    for (int it = 0; it < 6; ++it){
      int pair = it*8 + pr;
      int t0 = pair*2;
      size_t r0, r1;
      if (t0 < 64){
        int pix = (bh*8 + (t0>>3))*64 + bw*8 + (t0&7);
        r0 = (size_t)b*4096 + pix;
        r1 = r0 + 1;
      } else {
        int e = (b*64+n)*32 + (t0-64);
        r0 = (size_t)b*4096 + idxs[e];
        r1 = (size_t)b*4096 + idxs[e+1];
      }
      bf16x8 v0 = *(const bf16x8*)&xh[r0*HID + h*64 + dg*8];
      bf16x8 v1 = *(const bf16x8*)&xh[r1*HID + h*64 + dg*8];
      #pragma unroll
      for (int j = 0; j < 8; ++j){
        int d = dg*8 + j;
        int elem = (d*96 + t0) ^ (dg<<3);
        unsigned pk = (unsigned)(u16)v0[j] | ((unsigned)(u16)v1[j] << 16);
        *(unsigned*)&lKv[elem] = pk;
      }
    }
  }

  // ---- 3. wts + y prefetch ----
  float wv[8];
  {
    const float* wp = wts + (size_t)(b*64+n)*32 + (tid>>4)*8;
    float4 a = *(const float4*)wp, c = *(const float4*)(wp+4);
    wv[0]=a.x; wv[1]=a.y; wv[2]=a.z; wv[3]=a.w;
    wv[4]=c.x; wv[5]=c.y; wv[6]=c.z; wv[7]=c.w;
  }
  bf16x8 yv[8];
  {
    int pix = (bh*8 + (tid>>3))*64 + bw*8 + (tid&7);
    const u16* yrow = yb + ((size_t)b*4096 + pix)*HID + h*64;
    #pragma unroll
    for (int c = 0; c < 8; ++c)
      yv[c] = *(const bf16x8*)&yrow[c*8];
  }
  __syncthreads();   // drains vmcnt (aw gloads) + lgkm (kv writes)

  // ---- 4. A-fragments from LDS (swizzled read) + wts fold; MFMA ----
  const int lc = tid & 15, lk = tid >> 4;
  f32x4 acc[4][4] = {};
  #pragma unroll
  for (int ks = 0; ks < 3; ++ks){
    bf16x8 af[4];
    #pragma unroll
    for (int mi = 0; mi < 4; ++mi){
      int r = mi*16 + lc;
      int sr = ks*8 + lk*2;
      int key = r & 7;
      float4 f0 = *(const float4*)&lAw[(r*24 + (sr ^ key))*4];
      float4 f1 = *(const float4*)&lAw[(r*24 + ((sr+1) ^ key))*4];
      float t[8] = {f0.x,f0.y,f0.z,f0.w,f1.x,f1.y,f1.z,f1.w};
      #pragma unroll
      for (int j = 0; j < 8; ++j){
        float v = (ks == 2) ? t[j]*wv[j] : t[j];
        af[mi][j] = (short)f2bf(v);
      }
    }
    bf16x8 bv[4];
    #pragma unroll
    for (int nj = 0; nj < 4; ++nj){
      int d = nj*16 + lc;
      int idx = (d*96 + ks*32 + lk*8) ^ ((d>>3)<<3);
      bv[nj] = *(const bf16x8*)&lKv[idx];
    }
    #pragma unroll
    for (int mi = 0; mi < 4; ++mi)
      #pragma unroll
      for (int nj = 0; nj < 4; ++nj)
        acc[mi][nj] = __builtin_amdgcn_mfma_f32_16x16x32_bf16(af[mi], bv[nj], acc[mi][nj], 0,0,0);
  }

  // ---- 5. y transpose through LDS (kv region dead): yl[q][d], pitch 72 ----
  {
    const int q = tid;
    #pragma unroll
    for (int c = 0; c < 8; ++c)
      *(bf16x8*)&lKv[q*72 + c*8] = yv[c];
  }

  // ---- 6. epilogue: z = out * y, v2 store pattern, y from LDS ----
  #pragma unroll
  for (int mi = 0; mi < 4; ++mi){
    #pragma unroll
    for (int nj = 0; nj < 4; ++nj){
      int d = nj*16 + lc;
      size_t gcol = (size_t)h*64 + d;
      #pragma unroll
      for (int j = 0; j < 4; ++j){
        int q = mi*16 + lk*4 + j;
        int pix = (bh*8 + (q>>3))*64 + bw*8 + (q&7);
        size_t r = (size_t)b*4096 + pix;
        float yvf = bf2f((u16)lKv[q*72 + d]);
        zb[r*HID + gcol] = f2bf(acc[mi][nj][j] * yvf);
      }
    }
  }
}

// ---------------- GEMM2 v6: BK=32 dbuf, counted vmcnt (unchanged, passing) ----------------
__global__ __launch_bounds__(256)
void k_gemm2(const u16* __restrict__ zb, const u16* __restrict__ w2b,
             const float* __restrict__ b2, float* __restrict__ out)
{
  __shared__ short lds[16384];  // 32KB: buf stride 8192 shorts (A 4096 + B 4096)
  const int tid = threadIdx.x;
  const int w = tid>>6, lw = tid&63;
  const int wm = w>>1, wn = w&1;
  const int bid = blockIdx.x;
  const int xcd = bid & 7, ii = bid >> 3;
  const int m0 = (xcd*32 + ii/3) * 128;
  const int n0 = (ii%3) * 128;
  const int lc = lw & 15, lk = lw >> 4;

  f32x4 acc[4][4] = {};

  const int sl_g = (lw & 3) ^ ((lw >> 3) & 3);
  const int rsub = lw >> 2;
  const u16* gsrc[4]; int ldst[4];
  #pragma unroll
  for (int i = 0; i < 4; ++i){
    int c = w*4 + i;
    if (c < 8){
      int r = c*16 + rsub;
      gsrc[i] = zb + (size_t)(m0+r)*HID + sl_g*8;
      ldst[i] = c*512;
    } else {
      int cb = c - 8;
      int r = cb*16 + rsub;
      gsrc[i] = w2b + (size_t)(n0+r)*HID + sl_g*8;
      ldst[i] = 4096 + cb*512;
    }
  }
  auto STAGE = [&](int buf, int kt){
    #pragma unroll
    for (int i = 0; i < 4; ++i)
      gload_lds16(gsrc[i] + kt*32, &lds[ldst[i] + buf*8192]);
  };
  const int skey = (lc >> 1) & 3;
  auto COMPUTE = [&](int buf){
    const short* pa = lds + buf*8192;
    const short* pb = lds + buf*8192 + 4096;
    bf16x8 af[4], bb[4];
    #pragma unroll
    for (int mi=0; mi<4; ++mi){
      int row = wm*64 + mi*16 + lc;
      af[mi] = *(const bf16x8*)&pa[row*32 + (lk ^ skey)*8];
    }
    #pragma unroll
    for (int nj=0; nj<4; ++nj){
      int row = wn*64 + nj*16 + lc;
      bb[nj] = *(const bf16x8*)&pb[row*32 + (lk ^ skey)*8];
    }
    #pragma unroll
    for (int mi=0; mi<4; ++mi)
      #pragma unroll
      for (int nj=0; nj<4; ++nj)
        acc[mi][nj] = __builtin_amdgcn_mfma_f32_16x16x32_bf16(af[mi], bb[nj], acc[mi][nj], 0,0,0);
  };

  STAGE(0, 0);
  #pragma unroll 1
  for (int kt = 0; kt < 16; ++kt){
    if (kt < 15){
      STAGE((kt+1)&1, kt+1);
      asm volatile("s_waitcnt vmcnt(4)" ::: "memory");
    } else {
      asm volatile("s_waitcnt vmcnt(0)" ::: "memory");
    }
    __builtin_amdgcn_sched_barrier(0);
    __builtin_amdgcn_s_barrier();
    COMPUTE(kt&1);
    __builtin_amdgcn_sched_barrier(0);
    __builtin_amdgcn_s_barrier();
  }

  const int lr4 = lk*4;
  #pragma unroll
  for (int nj=0; nj<4; ++nj){
    int col = n0 + wn*64 + nj*16 + lc;
    float bias = b2[col];
    #pragma unroll
    for (int mi=0; mi<4; ++mi){
      #pragma unroll
      for (int j=0; j<4; ++j){
        int row = m0 + wm*64 + mi*16 + lr4 + j;
        out[(size_t)row*CH + col] = acc[mi][nj][j] + bias;
      }
    }
  }
}

extern "C" void kernel_launch(void* const* d_in, const int* in_sizes, int n_in,
                              void* d_out, int out_size, void* d_ws, size_t ws_size,
                              hipStream_t stream) {
  const float* x   = (const float*)d_in[0];
  const float* aw  = (const float*)d_in[1];
  const float* wts = (const float*)d_in[2];
  const float* w1  = (const float*)d_in[3];
  const float* b1  = (const float*)d_in[4];
  const float* w2  = (const float*)d_in[5];
  const float* b2  = (const float*)d_in[6];
  const int*   idx = (const int*)d_in[7];
  float* out = (float*)d_out;

  char* ws = (char*)d_ws;
  u16* x_bf  = (u16*)(ws);                              // 25165824
  u16* w1_bf = (u16*)(ws + 25165824);                   // 1179648
  u16* w2_bf = (u16*)(ws + 26345472);                   // 393216
  u16* xh_bf = (u16*)(ws + 26738688);                   // 33554432
  u16* y_bf  = (u16*)(ws + 60293120);                   // 33554432
  u16* z_bf  = (u16*)(ws + 93847552);                   // 33554432

  k_cvt3<<<2048, 256, 0, stream>>>(x, x_bf, w1, w1_bf, w2, w2_bf);

  k_gemm1<<<4096, 256, 0, stream>>>(x_bf, w1_bf, b1, xh_bf, y_bf);
  k_attn<<<NHD*8*64, 64, 0, stream>>>(aw, wts, idx, xh_bf, y_bf, z_bf);
  k_gemm2<<<768, 256, 0, stream>>>(z_bf, w2_bf, b2, out);
}

// Round 18
// 135.512 us; speedup vs baseline: 1.1212x; 1.0406x over previous
//
#include <hip/hip_runtime.h>
#include <hip/hip_bf16.h>
#include <stdint.h>

#define CH   384
#define HID  512
#define NHD  8
#define MTOT 32768   // B*H*W tokens

typedef __attribute__((ext_vector_type(8))) short bf16x8;
typedef __attribute__((ext_vector_type(4))) float f32x4;
typedef unsigned short u16;

__device__ __forceinline__ float bf2f(u16 v){ return __uint_as_float(((unsigned)v)<<16); }
__device__ __forceinline__ u16 f2bf(float f){
  unsigned u = __float_as_uint(f);
  return (u16)((u + 0x7fffu + ((u>>16)&1u)) >> 16);
}
__device__ __forceinline__ float fast_tanh(float s){
  float e = __expf(2.f*s);
  return 1.f - 2.f*__builtin_amdgcn_rcpf(e + 1.f);
}
__device__ __forceinline__ void gload_lds16(const void* g, void* l){
  __builtin_amdgcn_global_load_lds((const __attribute__((address_space(1))) void*)g,
                                   (__attribute__((address_space(3))) void*)l, 16, 0, 0);
}

// ---------------- fused fp32 -> bf16 convert (x, W1, W2 in one launch) ----------------
#define CVT_N1 (MTOT*CH/4)        // 3145728 float4s
#define CVT_N2 (3*HID*CH/4)       // 147456
#define CVT_N3 (CH*HID/4)         // 49152
__global__ void k_cvt3(const float* __restrict__ x,  u16* __restrict__ xo,
                       const float* __restrict__ w1, u16* __restrict__ w1o,
                       const float* __restrict__ w2, u16* __restrict__ w2o){
  const int total = CVT_N1 + CVT_N2 + CVT_N3;
  int i = blockIdx.x*blockDim.x + threadIdx.x;
  int stride = gridDim.x*blockDim.x;
  for (; i < total; i += stride){
    const float4* src; ushort4* dst; int k;
    if (i < CVT_N1){ src = (const float4*)x;  dst = (ushort4*)xo;  k = i; }
    else if (i < CVT_N1 + CVT_N2){ src = (const float4*)w1; dst = (ushort4*)w1o; k = i - CVT_N1; }
    else { src = (const float4*)w2; dst = (ushort4*)w2o; k = i - CVT_N1 - CVT_N2; }
    float4 v = src[k];
    ushort4 o; o.x=f2bf(v.x); o.y=f2bf(v.y); o.z=f2bf(v.z); o.w=f2bf(v.w);
    dst[k] = o;
  }
}

// ---------------- GEMM1 v8 (proven 63.5us): BM=128, BH=32, BK=64 ----------------
__global__ __launch_bounds__(256)
void k_gemm1(const u16* __restrict__ xb, const u16* __restrict__ w1b,
             const float* __restrict__ b1,
             u16* __restrict__ xh, u16* __restrict__ yb)
{
  __shared__ short lds[14336];  // A [0,8192)  B [8192,14336)  (28KB)
  const int tid = threadIdx.x;
  const int w = tid >> 6, lw = tid & 63;
  const int bid = blockIdx.x;
  const int xcd = bid & 7, ii = bid >> 3;
  const int m0 = (xcd*32 + (ii >> 4)) * 128;
  const int h0 = (ii & 15) * 32;
  const int lc = lw & 15, lk = lw >> 4;

  f32x4 acc[2][6] = {};   // [mi][seg*2+f]

  const int sl = (lw & 7) ^ (lw >> 3);
  const int rsub = lw >> 3;
  const u16* gsrc[7]; int ldst[7];
  #pragma unroll
  for (int i = 0; i < 7; ++i){
    int c = w*7 + i;
    if (c < 16){
      int r = c*8 + rsub;
      gsrc[i] = xb + (size_t)(m0 + r)*CH + sl*8;
      ldst[i] = c*512;
    } else {
      int rb = (c-16)*8 + rsub;                 // 0..95
      int grow = (rb >> 5)*HID + h0 + (rb & 31);
      gsrc[i] = w1b + (size_t)grow*CH + sl*8;
      ldst[i] = 8192 + (c-16)*512;
    }
  }

  #pragma unroll 1
  for (int kt = 0; kt < 6; ++kt){
    #pragma unroll
    for (int i = 0; i < 7; ++i)
      gload_lds16(gsrc[i] + kt*64, &lds[ldst[i]]);
    __syncthreads();
    #pragma unroll
    for (int ks = 0; ks < 2; ++ks){
      const int s = (ks*4 + lk) ^ (lc & 7);
      bf16x8 af[2], bfr[6];
      #pragma unroll
      for (int mi = 0; mi < 2; ++mi){
        int row = w*32 + mi*16 + lc;
        af[mi] = *(const bf16x8*)&lds[row*64 + s*8];
      }
      #pragma unroll
      for (int nj = 0; nj < 6; ++nj){
        int row = nj*16 + lc;
        bfr[nj] = *(const bf16x8*)&lds[8192 + row*64 + s*8];
      }
      #pragma unroll
      for (int mi = 0; mi < 2; ++mi)
        #pragma unroll
        for (int nj = 0; nj < 6; ++nj)
          acc[mi][nj] = __builtin_amdgcn_mfma_f32_16x16x32_bf16(af[mi], bfr[nj], acc[mi][nj], 0,0,0);
    }
    __syncthreads();
  }

  {
    short* epx = &lds[w*2560];          // 32 rows x 40-short pitch
    short* epy = &lds[w*2560 + 1280];
    float bs[2], bx[2], by[2];
    #pragma unroll
    for (int f = 0; f < 2; ++f){
      int col = h0 + f*16 + lc;
      bs[f] = b1[col]; bx[f] = b1[512 + col]; by[f] = b1[1024 + col];
    }
    #pragma unroll
    for (int mi = 0; mi < 2; ++mi)
      #pragma unroll
      for (int f = 0; f < 2; ++f)
        #pragma unroll
        for (int j = 0; j < 4; ++j){
          float sv = acc[mi][0+f][j] + bs[f];
          float xv = (acc[mi][2+f][j] + bx[f]) * fast_tanh(sv);
          float yv = acc[mi][4+f][j] + by[f];
          int row = mi*16 + lk*4 + j;
          epx[row*40 + f*16 + lc] = (short)f2bf(xv);
          epy[row*40 + f*16 + lc] = (short)f2bf(yv);
        }
    __syncthreads();
    const int row = lw >> 1, half = lw & 1;
    const size_t gbase = (size_t)(m0 + w*32 + row)*HID + h0 + half*16;
    #pragma unroll
    for (int q = 0; q < 2; ++q){
      bf16x8 v = *(const bf16x8*)&epx[row*40 + half*16 + q*8];
      *(bf16x8*)&xh[gbase + q*8] = v;
    }
    #pragma unroll
    for (int q = 0; q < 2; ++q){
      bf16x8 v = *(const bf16x8*)&epy[row*40 + half*16 + q*8];
      *(bf16x8*)&yb[gbase + q*8] = v;
    }
  }
}

// ---------------- Attention v10: 4 waves COOPERATE on one tile ----------------
// One 64x96 tile per 256-thr block: kv (12KB) + aw (24.6KB) staged cooperatively,
// shared by 4 waves -> 36.9KB serves 4 waves -> 4 blocks/CU = 16 waves/CU.
// Wave w computes output rows [16w,16w+16). All v9 access patterns preserved.
__global__ __launch_bounds__(256)
void k_attn(const float* __restrict__ aw, const float* __restrict__ wts,
            const int* __restrict__ idxs,
            const u16* __restrict__ xh, const u16* __restrict__ yb,
            u16* __restrict__ zb)
{
  __shared__ short ldsb[6144 + 12288];   // kv bf16 [0,6144); aw fp32 (24KB)
  short* lKv = ldsb;
  float* lAw = (float*)&ldsb[6144];
  const int tid0 = threadIdx.x;
  const int w = tid0 >> 6, lane = tid0 & 63;
  const int bid = blockIdx.x;    // ((h*8+b)*64+n)
  const int h = bid >> 9;
  const int b = (bid >> 6) & 7;
  const int n = bid & 63;
  const int bh = n >> 3, bw = n & 7;

  // ---- 1. aw staging: 24 chunks of 1KB; wave w -> chunks i*4+w ----
  {
    const float* awt = aw + (size_t)bid * 6144;
    #pragma unroll
    for (int i = 0; i < 6; ++i){
      int c = i*4 + w;
      int s = c*64 + lane;                // dest 16B-slice (0..1535)
      int row = s / 24;
      int sir = s - row*24;
      int src = row*24 + (sir ^ (row & 7));
      gload_lds16(awt + src*4, (char*)lAw + (size_t)c*1024);
    }
  }

  // ---- 2. kv gather (cooperative): 48 pairs x 8 dg = 384 slots ----
  {
    const int dg = tid0 & 7;
    // iter0: slots 0..255 -> pairs 0..31 (block-local, uniform branch)
    {
      int pair = tid0 >> 3;
      int t0 = pair*2;
      int pix = (bh*8 + (t0>>3))*64 + bw*8 + (t0&7);
      size_t r0 = (size_t)b*4096 + pix, r1 = r0 + 1;
      bf16x8 v0 = *(const bf16x8*)&xh[r0*HID + h*64 + dg*8];
      bf16x8 v1 = *(const bf16x8*)&xh[r1*HID + h*64 + dg*8];
      #pragma unroll
      for (int j = 0; j < 8; ++j){
        int d = dg*8 + j;
        int elem = (d*96 + t0) ^ (dg<<3);
        unsigned pk = (unsigned)(u16)v0[j] | ((unsigned)(u16)v1[j] << 16);
        *(unsigned*)&lKv[elem] = pk;
      }
    }
    // iter1: slots 256..383 (tid0<128) -> pairs 32..47 (gathered, uniform branch)
    if (tid0 < 128){
      int pr = tid0 >> 3;                 // 0..15
      int t0 = 64 + pr*2;
      int e = (b*64+n)*32 + pr*2;
      size_t r0 = (size_t)b*4096 + idxs[e];
      size_t r1 = (size_t)b*4096 + idxs[e+1];
      bf16x8 v0 = *(const bf16x8*)&xh[r0*HID + h*64 + dg*8];
      bf16x8 v1 = *(const bf16x8*)&xh[r1*HID + h*64 + dg*8];
      #pragma unroll
      for (int j = 0; j < 8; ++j){
        int d = dg*8 + j;
        int elem = (d*96 + t0) ^ (dg<<3);
        unsigned pk = (unsigned)(u16)v0[j] | ((unsigned)(u16)v1[j] << 16);
        *(unsigned*)&lKv[elem] = pk;
      }
    }
  }

  // ---- 3. wts (per wave) + y prefetch (thread -> (row q, quarter c4)) ----
  float wv[8];
  {
    const float* wp = wts + (size_t)(b*64+n)*32 + (lane>>4)*8;
    float4 a = *(const float4*)wp, c = *(const float4*)(wp+4);
    wv[0]=a.x; wv[1]=a.y; wv[2]=a.z; wv[3]=a.w;
    wv[4]=c.x; wv[5]=c.y; wv[6]=c.z; wv[7]=c.w;
  }
  bf16x8 yv0, yv1;
  const int yq = tid0 >> 2, yc = tid0 & 3;
  {
    int pix = (bh*8 + (yq>>3))*64 + bw*8 + (yq&7);
    const u16* yrow = yb + ((size_t)b*4096 + pix)*HID + h*64 + yc*16;
    yv0 = *(const bf16x8*)&yrow[0];
    yv1 = *(const bf16x8*)&yrow[8];
  }
  __syncthreads();   // all waves' kv writes + aw gloads visible

  // ---- 4. MFMA: wave w owns output rows [16w, 16w+16) ----
  const int lc = lane & 15, lk = lane >> 4;
  f32x4 acc[4] = {};
  #pragma unroll
  for (int ks = 0; ks < 3; ++ks){
    bf16x8 af;
    {
      int r = w*16 + lc;
      int sr = ks*8 + lk*2;
      int key = r & 7;
      float4 f0 = *(const float4*)&lAw[(r*24 + (sr ^ key))*4];
      float4 f1 = *(const float4*)&lAw[(r*24 + ((sr+1) ^ key))*4];
      float t[8] = {f0.x,f0.y,f0.z,f0.w,f1.x,f1.y,f1.z,f1.w};
      #pragma unroll
      for (int j = 0; j < 8; ++j){
        float v = (ks == 2) ? t[j]*wv[j] : t[j];
        af[j] = (short)f2bf(v);
      }
    }
    bf16x8 bv[4];
    #pragma unroll
    for (int nj = 0; nj < 4; ++nj){
      int d = nj*16 + lc;
      int idx = (d*96 + ks*32 + lk*8) ^ ((d>>3)<<3);
      bv[nj] = *(const bf16x8*)&lKv[idx];
    }
    #pragma unroll
    for (int nj = 0; nj < 4; ++nj)
      acc[nj] = __builtin_amdgcn_mfma_f32_16x16x32_bf16(af, bv[nj], acc[nj], 0,0,0);
  }
  __syncthreads();   // all kv reads done before y-transpose overwrites

  // ---- 5. y transpose through LDS: yl[q][d], pitch 72 (wave-local rows) ----
  *(bf16x8*)&lKv[yq*72 + yc*16    ] = yv0;
  *(bf16x8*)&lKv[yq*72 + yc*16 + 8] = yv1;
  // rows [16w,16w+16) written by wave w's own threads -> same-wave read below

  // ---- 6. epilogue: z = out * y, v2 store pattern (rows 16w..16w+15) ----
  #pragma unroll
  for (int nj = 0; nj < 4; ++nj){
    int d = nj*16 + lc;
    size_t gcol = (size_t)h*64 + d;
    #pragma unroll
    for (int j = 0; j < 4; ++j){
      int q = w*16 + lk*4 + j;
      int pix = (bh*8 + (q>>3))*64 + bw*8 + (q&7);
      size_t r = (size_t)b*4096 + pix;
      float yvf = bf2f((u16)lKv[q*72 + d]);
      zb[r*HID + gcol] = f2bf(acc[nj][j] * yvf);
    }
  }
}

// ---------------- GEMM2 v6: BK=32 dbuf, counted vmcnt (unchanged, passing) ----------------
__global__ __launch_bounds__(256)
void k_gemm2(const u16* __restrict__ zb, const u16* __restrict__ w2b,
             const float* __restrict__ b2, float* __restrict__ out)
{
  __shared__ short lds[16384];  // 32KB: buf stride 8192 shorts (A 4096 + B 4096)
  const int tid = threadIdx.x;
  const int w = tid>>6, lw = tid&63;
  const int wm = w>>1, wn = w&1;
  const int bid = blockIdx.x;
  const int xcd = bid & 7, ii = bid >> 3;
  const int m0 = (xcd*32 + ii/3) * 128;
  const int n0 = (ii%3) * 128;
  const int lc = lw & 15, lk = lw >> 4;

  f32x4 acc[4][4] = {};

  const int sl_g = (lw & 3) ^ ((lw >> 3) & 3);
  const int rsub = lw >> 2;
  const u16* gsrc[4]; int ldst[4];
  #pragma unroll
  for (int i = 0; i < 4; ++i){
    int c = w*4 + i;
    if (c < 8){
      int r = c*16 + rsub;
      gsrc[i] = zb + (size_t)(m0+r)*HID + sl_g*8;
      ldst[i] = c*512;
    } else {
      int cb = c - 8;
      int r = cb*16 + rsub;
      gsrc[i] = w2b + (size_t)(n0+r)*HID + sl_g*8;
      ldst[i] = 4096 + cb*512;
    }
  }
  auto STAGE = [&](int buf, int kt){
    #pragma unroll
    for (int i = 0; i < 4; ++i)
      gload_lds16(gsrc[i] + kt*32, &lds[ldst[i] + buf*8192]);
  };
  const int skey = (lc >> 1) & 3;
  auto COMPUTE = [&](int buf){
    const short* pa = lds + buf*8192;
    const short* pb = lds + buf*8192 + 4096;
    bf16x8 af[4], bb[4];
    #pragma unroll
    for (int mi=0; mi<4; ++mi){
      int row = wm*64 + mi*16 + lc;
      af[mi] = *(const bf16x8*)&pa[row*32 + (lk ^ skey)*8];
    }
    #pragma unroll
    for (int nj=0; nj<4; ++nj){
      int row = wn*64 + nj*16 + lc;
      bb[nj] = *(const bf16x8*)&pb[row*32 + (lk ^ skey)*8];
    }
    #pragma unroll
    for (int mi=0; mi<4; ++mi)
      #pragma unroll
      for (int nj=0; nj<4; ++nj)
        acc[mi][nj] = __builtin_amdgcn_mfma_f32_16x16x32_bf16(af[mi], bb[nj], acc[mi][nj], 0,0,0);
  };

  STAGE(0, 0);
  #pragma unroll 1
  for (int kt = 0; kt < 16; ++kt){
    if (kt < 15){
      STAGE((kt+1)&1, kt+1);
      asm volatile("s_waitcnt vmcnt(4)" ::: "memory");
    } else {
      asm volatile("s_waitcnt vmcnt(0)" ::: "memory");
    }
    __builtin_amdgcn_sched_barrier(0);
    __builtin_amdgcn_s_barrier();
    COMPUTE(kt&1);
    __builtin_amdgcn_sched_barrier(0);
    __builtin_amdgcn_s_barrier();
  }

  const int lr4 = lk*4;
  #pragma unroll
  for (int nj=0; nj<4; ++nj){
    int col = n0 + wn*64 + nj*16 + lc;
    float bias = b2[col];
    #pragma unroll
    for (int mi=0; mi<4; ++mi){
      #pragma unroll
      for (int j=0; j<4; ++j){
        int row = m0 + wm*64 + mi*16 + lr4 + j;
        out[(size_t)row*CH + col] = acc[mi][nj][j] + bias;
      }
    }
  }
}

extern "C" void kernel_launch(void* const* d_in, const int* in_sizes, int n_in,
                              void* d_out, int out_size, void* d_ws, size_t ws_size,
                              hipStream_t stream) {
  const float* x   = (const float*)d_in[0];
  const float* aw  = (const float*)d_in[1];
  const float* wts = (const float*)d_in[2];
  const float* w1  = (const float*)d_in[3];
  const float* b1  = (const float*)d_in[4];
  const float* w2  = (const float*)d_in[5];
  const float* b2  = (const float*)d_in[6];
  const int*   idx = (const int*)d_in[7];
  float* out = (float*)d_out;

  char* ws = (char*)d_ws;
  u16* x_bf  = (u16*)(ws);                              // 25165824
  u16* w1_bf = (u16*)(ws + 25165824);                   // 1179648
  u16* w2_bf = (u16*)(ws + 26345472);                   // 393216
  u16* xh_bf = (u16*)(ws + 26738688);                   // 33554432
  u16* y_bf  = (u16*)(ws + 60293120);                   // 33554432
  u16* z_bf  = (u16*)(ws + 93847552);                   // 33554432

  k_cvt3<<<2048, 256, 0, stream>>>(x, x_bf, w1, w1_bf, w2, w2_bf);

  k_gemm1<<<4096, 256, 0, stream>>>(x_bf, w1_bf, b1, xh_bf, y_bf);
  k_attn<<<NHD*8*64, 256, 0, stream>>>(aw, wts, idx, xh_bf, y_bf, z_bf);
  k_gemm2<<<768, 256, 0, stream>>>(z_bf, w2_bf, b2, out);
}